// Round 12
// baseline (112.496 us; speedup 1.0000x reference)
//
#include <hip/hip_runtime.h>
#include <math.h>

#define NTOK 96
#define EMBED 128
#define HEADS 4
#define HD 32
#define NROW (NTOK*NTOK)     // 9216
#define YT 16
#define NYT (NTOK/YT)        // 6

// ---- K1: head-major projection, dual stat layouts ----
// pF[v][h][u][32]; murF[v][h][u]; murE[u][h][v]  = {mu,rstd,Sg2,Sgb}
// 2304 blocks x 128 threads, 4 rows per block
__global__ __launch_bounds__(128) void k_proj(
    const float* __restrict__ x, const float* __restrict__ W,
    const float* __restrict__ b, const float* __restrict__ ln_g,
    const float* __restrict__ ln_b,
    float* __restrict__ pF, float4* __restrict__ murF,
    float4* __restrict__ murE) {
  const int r0 = blockIdx.x * 4;         // global row = u*96 + v
  const int U  = r0 / NTOK;
  const int v0 = r0 % NTOK;
  const int e  = threadIdx.x;            // 0..127
  __shared__ float xt[EMBED][4];
  #pragma unroll
  for (int k = 0; k < 4; ++k)
    xt[e][k] = x[(size_t)(r0 + k) * EMBED + e];
  __syncthreads();

  const float bias = b[e];
  float a0 = bias, a1 = bias, a2 = bias, a3 = bias;
  #pragma unroll 8
  for (int i = 0; i < EMBED; ++i) {
    const float wv = W[(size_t)i * EMBED + e];
    const float4 c = *(const float4*)&xt[i][0];
    a0 = fmaf(wv, c.x, a0); a1 = fmaf(wv, c.y, a1);
    a2 = fmaf(wv, c.z, a2); a3 = fmaf(wv, c.w, a3);
  }

  const int h = e >> 5;
  const int d = e & 31;
  const float gl = ln_g[d];
  const float bl = ln_b[d];
  const float gl2 = gl * gl;
  const float gvb = gl * bl;
  float accs[4] = {a0, a1, a2, a3};
  #pragma unroll
  for (int k = 0; k < 4; ++k) {
    const float val = accs[k];
    const int v = v0 + k;
    pF[(((size_t)v * HEADS + h) * NTOK + U) * HD + d] = val;
    float s1 = val, s2 = val * val, s3 = gl2 * val, s4 = gvb * val;
    #pragma unroll
    for (int m_ = 1; m_ < 32; m_ <<= 1) {
      s1 += __shfl_xor(s1, m_, 64);
      s2 += __shfl_xor(s2, m_, 64);
      s3 += __shfl_xor(s3, m_, 64);
      s4 += __shfl_xor(s4, m_, 64);
    }
    if (d == 0) {
      const float mu = s1 * (1.f / HD);
      const float var = fmaxf(s2 * (1.f / HD) - mu * mu, 0.f);
      float4 o; o.x = mu; o.y = rsqrtf(var + 1e-5f); o.z = s3; o.w = s4;
      murF[((size_t)v * HEADS + h) * NTOK + U] = o;
      murE[((size_t)U * HEADS + h) * NTOK + v] = o;
    }
  }
}

#define PR_QUAD(E4, F4, G2, T4) \
  T4.x = E4.x * F4.x; sraw = fmaf(G2.x, T4.x, sraw); m += T4.x; q = fmaf(T4.x, T4.x, q); \
  T4.y = E4.y * F4.y; sraw = fmaf(G2.y, T4.y, sraw); m += T4.y; q = fmaf(T4.y, T4.y, q); \
  T4.z = E4.z * F4.z; sraw = fmaf(G2.z, T4.z, sraw); m += T4.z; q = fmaf(T4.z, T4.z, q); \
  T4.w = E4.w * F4.w; sraw = fmaf(G2.w, T4.w, sraw); m += T4.w; q = fmaf(T4.w, T4.w, q);

#define AGG_QUAD(A4, T4) \
  A4.x = fmaf(w, T4.x, A4.x); A4.y = fmaf(w, T4.y, A4.y); \
  A4.z = fmaf(w, T4.z, A4.z); A4.w = fmaf(w, T4.w, A4.w);

#define RED_QUAD(A4, MASK) \
  A4.x += __shfl_xor(A4.x, MASK, 64); A4.y += __shfl_xor(A4.y, MASK, 64); \
  A4.z += __shfl_xor(A4.z, MASK, 64); A4.w += __shfl_xor(A4.w, MASK, 64);

// ---- K2: attention + product-LN aggregation, one head per block ----
// 2304 blocks (X fastest; then yt:6, h:4) x 512 threads = (y:16, ds:2, da:16)
// LDS: e_sm only (13.5 KB) -> 4 blocks/CU; stats stream dense from L2.
__global__ __launch_bounds__(512) void k_attn(
    const float* __restrict__ pF, const float4* __restrict__ murF,
    const float4* __restrict__ murE,
    const float* __restrict__ ln_g, const float* __restrict__ ln_b,
    float* __restrict__ agg) {
  const int bid = blockIdx.x;
  const int X   = bid % NTOK;
  const int t2i = bid / NTOK;            // 0..23
  const int y0  = (t2i % NYT) * YT;
  const int H   = t2i / NYT;

  const int tid = threadIdx.x;
  const int y   = tid >> 5;            // 0..15
  const int ds  = (tid >> 4) & 1;      // d-half
  const int da  = tid & 15;            // a-slice
  const int yy  = y0 + y;
  const int eoff = ds * 16;

  __shared__ float e_sm[NTOK][36];     // 13.5 KB (sole LDS use)

  // stage e-side: e[a] = p(X,a) = pF[a][H][X][.]
  {
    const int g0 = tid;                // 0..511
    const int a = g0 >> 3, qq = g0 & 7;
    *(float4*)&e_sm[a][qq * 4] =
        *(const float4*)&pF[(((size_t)a * HEADS + H) * NTOK + X) * HD + qq * 4];
  }
  if (tid < 256) {
    const int g1 = tid + 512;          // 512..767
    const int a = g1 >> 3, qq = g1 & 7;
    *(float4*)&e_sm[a][qq * 4] =
        *(const float4*)&pF[(((size_t)a * HEADS + H) * NTOK + X) * HD + qq * 4];
  }

  // LN constants: T2=sum g^2, Vb=sum g*b, Wb=sum b^2, Mg2=max g^2
  const float glx = ln_g[tid & 31];
  const float blx = ln_b[tid & 31];
  float T2c = glx * glx, Vbc = glx * blx, Wbc = blx * blx, Mg2 = glx * glx;
  #pragma unroll
  for (int m_ = 1; m_ < 32; m_ <<= 1) {
    T2c += __shfl_xor(T2c, m_, 64);
    Vbc += __shfl_xor(Vbc, m_, 64);
    Wbc += __shfl_xor(Wbc, m_, 64);
    Mg2 = fmaxf(Mg2, __shfl_xor(Mg2, m_, 64));
  }
  // score bound: |sc| <= (64*Mg2 + 2*Wb) / sqrt(32)
  const float SB = (64.f * Mg2 + 2.f * Wbc) * 0.17677669529663687f;

  // g^2 weights for this lane's d-range (reloaded in epilogue, not kept live)
  float4 g2q0, g2q1, g2q2, g2q3;
  {
    const float4 t0 = *(const float4*)&ln_g[eoff];
    const float4 t1 = *(const float4*)&ln_g[eoff + 4];
    const float4 t2 = *(const float4*)&ln_g[eoff + 8];
    const float4 t3 = *(const float4*)&ln_g[eoff + 12];
    g2q0.x = t0.x*t0.x; g2q0.y = t0.y*t0.y; g2q0.z = t0.z*t0.z; g2q0.w = t0.w*t0.w;
    g2q1.x = t1.x*t1.x; g2q1.y = t1.y*t1.y; g2q1.z = t1.z*t1.z; g2q1.w = t1.w*t1.w;
    g2q2.x = t2.x*t2.x; g2q2.y = t2.y*t2.y; g2q2.z = t2.z*t2.z; g2q2.w = t2.w*t2.w;
    g2q3.x = t3.x*t3.x; g2q3.y = t3.y*t3.y; g2q3.z = t3.z*t3.z; g2q3.w = t3.w*t3.w;
  }
  __syncthreads();

  // dense streams: pF[yy][H][a][.], murF[yy][H][a], murE[X][H][a]
  const float* fbase  = pF + (((size_t)yy * HEADS + H) * NTOK) * HD + eoff;
  const float4* mfb   = murF + ((size_t)yy * HEADS + H) * NTOK;
  const float4* meb   = murE + ((size_t)X * HEADS + H) * NTOK;

  float4 acc0 = {0,0,0,0}, acc1 = {0,0,0,0}, acc2 = {0,0,0,0}, acc3 = {0,0,0,0};
  float den = 0.f, cc = 0.f;

  #pragma unroll 2
  for (int ia = 0; ia < 6; ++ia) {
    const int a = ia * 16 + da;
    const float4* fp = (const float4*)(fbase + (size_t)a * HD);
    const float4 f0 = fp[0], f1 = fp[1], f2 = fp[2], f3 = fp[3];
    const float4 mrF = mfb[a];
    const float4 mrE = meb[a];
    const float4 e0 = *(const float4*)&e_sm[a][eoff];
    const float4 e1 = *(const float4*)&e_sm[a][eoff + 4];
    const float4 e2 = *(const float4*)&e_sm[a][eoff + 8];
    const float4 e3 = *(const float4*)&e_sm[a][eoff + 12];

    float sraw = 0.f, m = 0.f, q = 0.f;
    float4 t0, t1, t2, t3;
    PR_QUAD(e0, f0, g2q0, t0);
    PR_QUAD(e1, f1, g2q1, t1);
    PR_QUAD(e2, f2, g2q2, t2);
    PR_QUAD(e3, f3, g2q3, t3);

    // combine d-halves (xor ds bit)
    sraw += __shfl_xor(sraw, 16, 64);
    m    += __shfl_xor(m,    16, 64);
    q    += __shfl_xor(q,    16, 64);

    // LN'd score from raw moments
    const float muE = mrE.x, rE = mrE.y, Sg2E = mrE.z, SgbE = mrE.w;
    const float muF = mrF.x, rF = mrF.y, Sg2F = mrF.z, SgbF = mrF.w;
    const float inner = sraw - muF * Sg2E - muE * Sg2F + muE * muF * T2c;
    const float sfull = rE * rF * inner
                      + rE * (SgbE - muE * Vbc)
                      + rF * (SgbF - muF * Vbc) + Wbc;
    const float sc = sfull * 0.17677669529663687f;   // 1/sqrt(32)

    // product-LN stats
    const float mu = m * (1.f / HD);
    const float var = fmaxf(fmaf(-mu, mu, q * (1.f / HD)), 0.f);
    const float r = rsqrtf(var + 1e-5f);

    const float ex = __expf(sc - SB);   // <= 1 by construction
    const float w = ex * r;
    den += ex;
    cc  = fmaf(w, mu, cc);
    AGG_QUAD(acc0, t0);
    AGG_QUAD(acc1, t1);
    AGG_QUAD(acc2, t2);
    AGG_QUAD(acc3, t3);
  }

  // cross-a reduction over the 16 da lanes
  #pragma unroll
  for (int mask = 1; mask <= 8; mask <<= 1) {
    den += __shfl_xor(den, mask, 64);
    cc  += __shfl_xor(cc,  mask, 64);
    RED_QUAD(acc0, mask);
    RED_QUAD(acc1, mask);
    RED_QUAD(acc2, mask);
    RED_QUAD(acc3, mask);
  }

  if (da == 0) {
    const float4 gq0 = *(const float4*)&ln_g[eoff];
    const float4 gq1 = *(const float4*)&ln_g[eoff + 4];
    const float4 gq2 = *(const float4*)&ln_g[eoff + 8];
    const float4 gq3 = *(const float4*)&ln_g[eoff + 12];
    const float4 bq0 = *(const float4*)&ln_b[eoff];
    const float4 bq1 = *(const float4*)&ln_b[eoff + 4];
    const float4 bq2 = *(const float4*)&ln_b[eoff + 8];
    const float4 bq3 = *(const float4*)&ln_b[eoff + 12];
    const float inv = 1.f / den;
    float4 o0, o1, o2, o3;
    o0.x = fmaf(gq0.x, (acc0.x - cc) * inv, bq0.x);
    o0.y = fmaf(gq0.y, (acc0.y - cc) * inv, bq0.y);
    o0.z = fmaf(gq0.z, (acc0.z - cc) * inv, bq0.z);
    o0.w = fmaf(gq0.w, (acc0.w - cc) * inv, bq0.w);
    o1.x = fmaf(gq1.x, (acc1.x - cc) * inv, bq1.x);
    o1.y = fmaf(gq1.y, (acc1.y - cc) * inv, bq1.y);
    o1.z = fmaf(gq1.z, (acc1.z - cc) * inv, bq1.z);
    o1.w = fmaf(gq1.w, (acc1.w - cc) * inv, bq1.w);
    o2.x = fmaf(gq2.x, (acc2.x - cc) * inv, bq2.x);
    o2.y = fmaf(gq2.y, (acc2.y - cc) * inv, bq2.y);
    o2.z = fmaf(gq2.z, (acc2.z - cc) * inv, bq2.z);
    o2.w = fmaf(gq2.w, (acc2.w - cc) * inv, bq2.w);
    o3.x = fmaf(gq3.x, (acc3.x - cc) * inv, bq3.x);
    o3.y = fmaf(gq3.y, (acc3.y - cc) * inv, bq3.y);
    o3.z = fmaf(gq3.z, (acc3.z - cc) * inv, bq3.z);
    o3.w = fmaf(gq3.w, (acc3.w - cc) * inv, bq3.w);
    float* op = agg + ((size_t)(X * NTOK + yy)) * EMBED + H * HD + eoff;
    *(float4*)&op[0]  = o0;
    *(float4*)&op[4]  = o1;
    *(float4*)&op[8]  = o2;
    *(float4*)&op[12] = o3;
  }
}

// ---- K3: out = LN([x, agg] @ Wf + bf) ----
// 1152 blocks x 256 threads, 8 rows per block
__global__ __launch_bounds__(256) void k_final(
    const float* __restrict__ x, const float* __restrict__ agg,
    const float* __restrict__ Wf, const float* __restrict__ bf,
    const float* __restrict__ g2, const float* __restrict__ b2,
    float* __restrict__ out) {
  const int r0 = blockIdx.x * 8;
  const int tid = threadIdx.x;
  const int e = tid & 127;
  const int rh = tid >> 7;               // rows rh*4 .. rh*4+3
  __shared__ float ct[2 * EMBED][12];    // transposed [x|agg], 12.3 KB
  __shared__ float red_sm[4][4][2];

  #pragma unroll
  for (int i = 0; i < 8; ++i) {
    const int g = tid + i * 256;         // 0..2047
    const int yl = g >> 8, col = g & 255;
    const size_t row = (size_t)(r0 + yl);
    const float v = (col < 128) ? x[row * EMBED + col]
                                : agg[row * EMBED + (col - 128)];
    ct[col][yl] = v;
  }
  __syncthreads();

  const float bias = bf[e];
  float acc4[4] = {bias, bias, bias, bias};
  #pragma unroll 8
  for (int i = 0; i < 2 * EMBED; ++i) {
    const float wv = Wf[(size_t)i * EMBED + e];
    const float4 c0 = *(const float4*)&ct[i][rh * 4];
    acc4[0] = fmaf(wv, c0.x, acc4[0]); acc4[1] = fmaf(wv, c0.y, acc4[1]);
    acc4[2] = fmaf(wv, c0.z, acc4[2]); acc4[3] = fmaf(wv, c0.w, acc4[3]);
  }

  const int wid = tid >> 6;
  #pragma unroll
  for (int k = 0; k < 4; ++k) {
    float s1 = acc4[k], s2 = acc4[k] * acc4[k];
    #pragma unroll
    for (int m_ = 1; m_ < 64; m_ <<= 1) {
      s1 += __shfl_xor(s1, m_, 64);
      s2 += __shfl_xor(s2, m_, 64);
    }
    if ((tid & 63) == 0) { red_sm[wid][k][0] = s1; red_sm[wid][k][1] = s2; }
  }
  __syncthreads();

  const float gg = g2[e], bb = b2[e];
  #pragma unroll
  for (int k = 0; k < 4; ++k) {
    const float S1 = red_sm[wid][k][0] + red_sm[wid ^ 1][k][0];
    const float S2 = red_sm[wid][k][1] + red_sm[wid ^ 1][k][1];
    const float mu = S1 * (1.f / EMBED);
    const float var = fmaxf(S2 * (1.f / EMBED) - mu * mu, 0.f);
    const float rstd = rsqrtf(var + 1e-5f);
    out[(size_t)(r0 + rh * 4 + k) * EMBED + e] = (acc4[k] - mu) * rstd * gg + bb;
  }
}

extern "C" void kernel_launch(void* const* d_in, const int* in_sizes, int n_in,
                              void* d_out, int out_size, void* d_ws, size_t ws_size,
                              hipStream_t stream) {
  const float* x    = (const float*)d_in[0];
  const float* W    = (const float*)d_in[1];
  const float* b    = (const float*)d_in[2];
  const float* ln_g = (const float*)d_in[3];
  const float* ln_b = (const float*)d_in[4];
  const float* Wf   = (const float*)d_in[5];
  const float* bf   = (const float*)d_in[6];
  const float* g2   = (const float*)d_in[7];
  const float* b2   = (const float*)d_in[8];
  float* out = (float*)d_out;

  float*  pF   = (float*)d_ws;                         // NROW*128 floats
  float4* murF = (float4*)(pF + (size_t)NROW * EMBED); // NROW*4 float4
  float4* murE = murF + (size_t)NROW * HEADS;          // NROW*4 float4
  float*  agg  = (float*)(murE + (size_t)NROW * HEADS);

  k_proj<<<NROW / 4, 128, 0, stream>>>(x, W, b, ln_g, ln_b, pF, murF, murE);
  k_attn<<<NTOK * NYT * HEADS, 512, 0, stream>>>(pF, murF, murE, ln_g, ln_b, agg);
  k_final<<<NROW / 8, 256, 0, stream>>>(x, agg, Wf, bf, g2, b2, out);
}

// Round 13
// 111.829 us; speedup vs baseline: 1.0060x; 1.0060x over previous
//
#include <hip/hip_runtime.h>
#include <math.h>

#define NTOK 96
#define EMBED 128
#define HEADS 4
#define HD 32
#define NROW (NTOK*NTOK)     // 9216
#define YT 8
#define NYT (NTOK/YT)        // 12

// ---- K1: head-major projection, dual stat layouts ----
// pF[v][h][u][32]; murF[v][h][u]; murE[u][h][v]  = {mu,rstd,Sg2,Sgb}
__global__ __launch_bounds__(128) void k_proj(
    const float* __restrict__ x, const float* __restrict__ W,
    const float* __restrict__ b, const float* __restrict__ ln_g,
    const float* __restrict__ ln_b,
    float* __restrict__ pF, float4* __restrict__ murF,
    float4* __restrict__ murE) {
  const int r0 = blockIdx.x * 4;         // global row = u*96 + v
  const int U  = r0 / NTOK;
  const int v0 = r0 % NTOK;
  const int e  = threadIdx.x;            // 0..127
  __shared__ float xt[EMBED][4];
  #pragma unroll
  for (int k = 0; k < 4; ++k)
    xt[e][k] = x[(size_t)(r0 + k) * EMBED + e];
  __syncthreads();

  const float bias = b[e];
  float a0 = bias, a1 = bias, a2 = bias, a3 = bias;
  #pragma unroll 8
  for (int i = 0; i < EMBED; ++i) {
    const float wv = W[(size_t)i * EMBED + e];
    const float4 c = *(const float4*)&xt[i][0];
    a0 = fmaf(wv, c.x, a0); a1 = fmaf(wv, c.y, a1);
    a2 = fmaf(wv, c.z, a2); a3 = fmaf(wv, c.w, a3);
  }

  const int h = e >> 5;
  const int d = e & 31;
  const float gl = ln_g[d];
  const float bl = ln_b[d];
  const float gl2 = gl * gl;
  const float gvb = gl * bl;
  float accs[4] = {a0, a1, a2, a3};
  #pragma unroll
  for (int k = 0; k < 4; ++k) {
    const float val = accs[k];
    const int v = v0 + k;
    pF[(((size_t)v * HEADS + h) * NTOK + U) * HD + d] = val;
    float s1 = val, s2 = val * val, s3 = gl2 * val, s4 = gvb * val;
    #pragma unroll
    for (int m_ = 1; m_ < 32; m_ <<= 1) {
      s1 += __shfl_xor(s1, m_, 64);
      s2 += __shfl_xor(s2, m_, 64);
      s3 += __shfl_xor(s3, m_, 64);
      s4 += __shfl_xor(s4, m_, 64);
    }
    if (d == 0) {
      const float mu = s1 * (1.f / HD);
      const float var = fmaxf(s2 * (1.f / HD) - mu * mu, 0.f);
      float4 o; o.x = mu; o.y = rsqrtf(var + 1e-5f); o.z = s3; o.w = s4;
      murF[((size_t)v * HEADS + h) * NTOK + U] = o;
      murE[((size_t)U * HEADS + h) * NTOK + v] = o;
    }
  }
}

// ---- K2: attention + product-LN aggregation ----
// 4608 blocks (X fastest; yt:12, h:4) x 256 threads = (y:8, da:32).
// Lane owns FULL 32-d of one a per iteration: NO in-loop cross-lane ops.
__global__ __launch_bounds__(256) void k_attn(
    const float* __restrict__ pF, const float4* __restrict__ murF,
    const float4* __restrict__ murE,
    const float* __restrict__ ln_g, const float* __restrict__ ln_b,
    float* __restrict__ agg) {
  const int bid = blockIdx.x;
  const int X   = bid % NTOK;
  const int t2i = bid / NTOK;            // 0..47
  const int y0  = (t2i % NYT) * YT;
  const int H   = t2i / NYT;

  const int tid = threadIdx.x;
  const int y   = tid >> 5;            // 0..7
  const int da  = tid & 31;            // a-slice (32 lanes)
  const int yy  = y0 + y;

  __shared__ float e_sm[NTOK][36];     // 13.8 KB (sole LDS use)

  // stage e-side: e[a] = p(X,a) = pF[a][H][X][.]
  #pragma unroll
  for (int i = 0; i < 3; ++i) {
    const int g = tid + i * 256;       // 0..767
    const int a = g >> 3, qq = g & 7;
    *(float4*)&e_sm[a][qq * 4] =
        *(const float4*)&pF[(((size_t)a * HEADS + H) * NTOK + X) * HD + qq * 4];
  }

  // LN constants: T2=sum g^2, Vb=sum g*b, Wb=sum b^2, Mg2=max g^2
  const float glx = ln_g[tid & 31];
  const float blx = ln_b[tid & 31];
  float T2c = glx * glx, Vbc = glx * blx, Wbc = blx * blx, Mg2 = glx * glx;
  #pragma unroll
  for (int m_ = 1; m_ < 32; m_ <<= 1) {
    T2c += __shfl_xor(T2c, m_, 64);
    Vbc += __shfl_xor(Vbc, m_, 64);
    Wbc += __shfl_xor(Wbc, m_, 64);
    Mg2 = fmaxf(Mg2, __shfl_xor(Mg2, m_, 64));
  }
  const float SB = (64.f * Mg2 + 2.f * Wbc) * 0.17677669529663687f;

  // g^2 as wave-uniform scalars (compile-time indices -> SGPRs)
  float g2c[32];
  #pragma unroll
  for (int d = 0; d < 32; ++d) { const float g = ln_g[d]; g2c[d] = g * g; }
  __syncthreads();

  const float* fbase = pF + (((size_t)yy * HEADS + H) * NTOK) * HD;
  const float4* mfb  = murF + ((size_t)yy * HEADS + H) * NTOK;
  const float4* meb  = murE + ((size_t)X * HEADS + H) * NTOK;

  float4 acc[8];
  #pragma unroll
  for (int k = 0; k < 8; ++k) acc[k] = make_float4(0.f, 0.f, 0.f, 0.f);
  float den = 0.f, cc = 0.f;

  #pragma unroll
  for (int ia = 0; ia < 3; ++ia) {
    const int a = ia * 32 + da;
    const float4* fp = (const float4*)(fbase + (size_t)a * HD);
    float4 f[8], e[8], t[8];
    #pragma unroll
    for (int k = 0; k < 8; ++k) f[k] = fp[k];
    const float4 mrF = mfb[a];
    const float4 mrE = meb[a];
    #pragma unroll
    for (int k = 0; k < 8; ++k) e[k] = *(const float4*)&e_sm[a][k * 4];

    float s0 = 0.f, s1 = 0.f, m0 = 0.f, m1 = 0.f, q0 = 0.f, q1 = 0.f;
    #pragma unroll
    for (int k = 0; k < 4; ++k) {
      t[k].x = e[k].x * f[k].x; s0 = fmaf(g2c[k*4+0], t[k].x, s0); m0 += t[k].x; q0 = fmaf(t[k].x, t[k].x, q0);
      t[k].y = e[k].y * f[k].y; s0 = fmaf(g2c[k*4+1], t[k].y, s0); m0 += t[k].y; q0 = fmaf(t[k].y, t[k].y, q0);
      t[k].z = e[k].z * f[k].z; s0 = fmaf(g2c[k*4+2], t[k].z, s0); m0 += t[k].z; q0 = fmaf(t[k].z, t[k].z, q0);
      t[k].w = e[k].w * f[k].w; s0 = fmaf(g2c[k*4+3], t[k].w, s0); m0 += t[k].w; q0 = fmaf(t[k].w, t[k].w, q0);
    }
    #pragma unroll
    for (int k = 4; k < 8; ++k) {
      t[k].x = e[k].x * f[k].x; s1 = fmaf(g2c[k*4+0], t[k].x, s1); m1 += t[k].x; q1 = fmaf(t[k].x, t[k].x, q1);
      t[k].y = e[k].y * f[k].y; s1 = fmaf(g2c[k*4+1], t[k].y, s1); m1 += t[k].y; q1 = fmaf(t[k].y, t[k].y, q1);
      t[k].z = e[k].z * f[k].z; s1 = fmaf(g2c[k*4+2], t[k].z, s1); m1 += t[k].z; q1 = fmaf(t[k].z, t[k].z, q1);
      t[k].w = e[k].w * f[k].w; s1 = fmaf(g2c[k*4+3], t[k].w, s1); m1 += t[k].w; q1 = fmaf(t[k].w, t[k].w, q1);
    }
    const float sraw = s0 + s1;
    const float msum = m0 + m1;
    const float qsum = q0 + q1;

    // LN'd score from raw moments (all per-lane)
    const float muE = mrE.x, rE = mrE.y, Sg2E = mrE.z, SgbE = mrE.w;
    const float muF = mrF.x, rF = mrF.y, Sg2F = mrF.z, SgbF = mrF.w;
    const float inner = sraw - muF * Sg2E - muE * Sg2F + muE * muF * T2c;
    const float sfull = rE * rF * inner
                      + rE * (SgbE - muE * Vbc)
                      + rF * (SgbF - muF * Vbc) + Wbc;
    const float sc = sfull * 0.17677669529663687f;   // 1/sqrt(32)

    const float mu = msum * (1.f / HD);
    const float var = fmaxf(fmaf(-mu, mu, qsum * (1.f / HD)), 0.f);
    const float r = rsqrtf(var + 1e-5f);

    const float ex = __expf(sc - SB);   // <= 1 by construction
    const float w = ex * r;
    den += ex;
    cc  = fmaf(w, mu, cc);
    #pragma unroll
    for (int k = 0; k < 8; ++k) {
      acc[k].x = fmaf(w, t[k].x, acc[k].x);
      acc[k].y = fmaf(w, t[k].y, acc[k].y);
      acc[k].z = fmaf(w, t[k].z, acc[k].z);
      acc[k].w = fmaf(w, t[k].w, acc[k].w);
    }
  }

  // one-time cross-a butterfly over the 32 da lanes
  #pragma unroll
  for (int mask = 1; mask <= 16; mask <<= 1) {
    den += __shfl_xor(den, mask, 64);
    cc  += __shfl_xor(cc,  mask, 64);
    #pragma unroll
    for (int k = 0; k < 8; ++k) {
      acc[k].x += __shfl_xor(acc[k].x, mask, 64);
      acc[k].y += __shfl_xor(acc[k].y, mask, 64);
      acc[k].z += __shfl_xor(acc[k].z, mask, 64);
      acc[k].w += __shfl_xor(acc[k].w, mask, 64);
    }
  }

  if (da == 0) {
    const float inv = 1.f / den;
    float* op = agg + ((size_t)(X * NTOK + yy)) * EMBED + H * HD;
    #pragma unroll
    for (int k = 0; k < 8; ++k) {
      const float4 gq = *(const float4*)&ln_g[k * 4];
      const float4 bq = *(const float4*)&ln_b[k * 4];
      float4 o;
      o.x = fmaf(gq.x, (acc[k].x - cc) * inv, bq.x);
      o.y = fmaf(gq.y, (acc[k].y - cc) * inv, bq.y);
      o.z = fmaf(gq.z, (acc[k].z - cc) * inv, bq.z);
      o.w = fmaf(gq.w, (acc[k].w - cc) * inv, bq.w);
      *(float4*)&op[k * 4] = o;
    }
  }
}

// ---- K3: out = LN([x, agg] @ Wf + bf) ----
// 1152 blocks x 256 threads, 8 rows per block
__global__ __launch_bounds__(256) void k_final(
    const float* __restrict__ x, const float* __restrict__ agg,
    const float* __restrict__ Wf, const float* __restrict__ bf,
    const float* __restrict__ g2, const float* __restrict__ b2,
    float* __restrict__ out) {
  const int r0 = blockIdx.x * 8;
  const int tid = threadIdx.x;
  const int e = tid & 127;
  const int rh = tid >> 7;               // rows rh*4 .. rh*4+3
  __shared__ float ct[2 * EMBED][12];    // transposed [x|agg], 12.3 KB
  __shared__ float red_sm[4][4][2];

  #pragma unroll
  for (int i = 0; i < 8; ++i) {
    const int g = tid + i * 256;         // 0..2047
    const int yl = g >> 8, col = g & 255;
    const size_t row = (size_t)(r0 + yl);
    const float v = (col < 128) ? x[row * EMBED + col]
                                : agg[row * EMBED + (col - 128)];
    ct[col][yl] = v;
  }
  __syncthreads();

  const float bias = bf[e];
  float acc4[4] = {bias, bias, bias, bias};
  #pragma unroll 8
  for (int i = 0; i < 2 * EMBED; ++i) {
    const float wv = Wf[(size_t)i * EMBED + e];
    const float4 c0 = *(const float4*)&ct[i][rh * 4];
    acc4[0] = fmaf(wv, c0.x, acc4[0]); acc4[1] = fmaf(wv, c0.y, acc4[1]);
    acc4[2] = fmaf(wv, c0.z, acc4[2]); acc4[3] = fmaf(wv, c0.w, acc4[3]);
  }

  const int wid = tid >> 6;
  #pragma unroll
  for (int k = 0; k < 4; ++k) {
    float s1 = acc4[k], s2 = acc4[k] * acc4[k];
    #pragma unroll
    for (int m_ = 1; m_ < 64; m_ <<= 1) {
      s1 += __shfl_xor(s1, m_, 64);
      s2 += __shfl_xor(s2, m_, 64);
    }
    if ((tid & 63) == 0) { red_sm[wid][k][0] = s1; red_sm[wid][k][1] = s2; }
  }
  __syncthreads();

  const float gg = g2[e], bb = b2[e];
  #pragma unroll
  for (int k = 0; k < 4; ++k) {
    const float S1 = red_sm[wid][k][0] + red_sm[wid ^ 1][k][0];
    const float S2 = red_sm[wid][k][1] + red_sm[wid ^ 1][k][1];
    const float mu = S1 * (1.f / EMBED);
    const float var = fmaxf(S2 * (1.f / EMBED) - mu * mu, 0.f);
    const float rstd = rsqrtf(var + 1e-5f);
    out[(size_t)(r0 + rh * 4 + k) * EMBED + e] = (acc4[k] - mu) * rstd * gg + bb;
  }
}

extern "C" void kernel_launch(void* const* d_in, const int* in_sizes, int n_in,
                              void* d_out, int out_size, void* d_ws, size_t ws_size,
                              hipStream_t stream) {
  const float* x    = (const float*)d_in[0];
  const float* W    = (const float*)d_in[1];
  const float* b    = (const float*)d_in[2];
  const float* ln_g = (const float*)d_in[3];
  const float* ln_b = (const float*)d_in[4];
  const float* Wf   = (const float*)d_in[5];
  const float* bf   = (const float*)d_in[6];
  const float* g2   = (const float*)d_in[7];
  const float* b2   = (const float*)d_in[8];
  float* out = (float*)d_out;

  float*  pF   = (float*)d_ws;                         // NROW*128 floats
  float4* murF = (float4*)(pF + (size_t)NROW * EMBED); // NROW*4 float4
  float4* murE = murF + (size_t)NROW * HEADS;          // NROW*4 float4
  float*  agg  = (float*)(murE + (size_t)NROW * HEADS);

  k_proj<<<NROW / 4, 128, 0, stream>>>(x, W, b, ln_g, ln_b, pF, murF, murE);
  k_attn<<<NTOK * NYT * HEADS, 256, 0, stream>>>(pF, murF, murE, ln_g, ln_b, agg);
  k_final<<<NROW / 8, 256, 0, stream>>>(x, agg, Wf, bf, g2, b2, out);
}

// Round 14
// 111.272 us; speedup vs baseline: 1.0110x; 1.0050x over previous
//
#include <hip/hip_runtime.h>
#include <math.h>

#define NTOK 96
#define EMBED 128
#define HEADS 4
#define HD 32
#define NROW (NTOK*NTOK)     // 9216
#define YT 16
#define NYT (NTOK/YT)        // 6

// ---- K1: head-major projection, dual stat layouts ----
// pF[v][h][u][32]; murF[v][h][u]; murE[u][h][v]  = {mu,rstd,Sg2,Sgb}
__global__ __launch_bounds__(128) void k_proj(
    const float* __restrict__ x, const float* __restrict__ W,
    const float* __restrict__ b, const float* __restrict__ ln_g,
    const float* __restrict__ ln_b,
    float* __restrict__ pF, float4* __restrict__ murF,
    float4* __restrict__ murE) {
  const int r0 = blockIdx.x * 4;         // global row = u*96 + v
  const int U  = r0 / NTOK;
  const int v0 = r0 % NTOK;
  const int e  = threadIdx.x;            // 0..127
  __shared__ float xt[EMBED][4];
  #pragma unroll
  for (int k = 0; k < 4; ++k)
    xt[e][k] = x[(size_t)(r0 + k) * EMBED + e];
  __syncthreads();

  const float bias = b[e];
  float a0 = bias, a1 = bias, a2 = bias, a3 = bias;
  #pragma unroll 8
  for (int i = 0; i < EMBED; ++i) {
    const float wv = W[(size_t)i * EMBED + e];
    const float4 c = *(const float4*)&xt[i][0];
    a0 = fmaf(wv, c.x, a0); a1 = fmaf(wv, c.y, a1);
    a2 = fmaf(wv, c.z, a2); a3 = fmaf(wv, c.w, a3);
  }

  const int h = e >> 5;
  const int d = e & 31;
  const float gl = ln_g[d];
  const float bl = ln_b[d];
  const float gl2 = gl * gl;
  const float gvb = gl * bl;
  float accs[4] = {a0, a1, a2, a3};
  #pragma unroll
  for (int k = 0; k < 4; ++k) {
    const float val = accs[k];
    const int v = v0 + k;
    pF[(((size_t)v * HEADS + h) * NTOK + U) * HD + d] = val;
    float s1 = val, s2 = val * val, s3 = gl2 * val, s4 = gvb * val;
    #pragma unroll
    for (int m_ = 1; m_ < 32; m_ <<= 1) {
      s1 += __shfl_xor(s1, m_, 64);
      s2 += __shfl_xor(s2, m_, 64);
      s3 += __shfl_xor(s3, m_, 64);
      s4 += __shfl_xor(s4, m_, 64);
    }
    if (d == 0) {
      const float mu = s1 * (1.f / HD);
      const float var = fmaxf(s2 * (1.f / HD) - mu * mu, 0.f);
      float4 o; o.x = mu; o.y = rsqrtf(var + 1e-5f); o.z = s3; o.w = s4;
      murF[((size_t)v * HEADS + h) * NTOK + U] = o;
      murE[((size_t)U * HEADS + h) * NTOK + v] = o;
    }
  }
}

#define PR_QUAD(E4, F4, G2, T4) \
  T4.x = E4.x * F4.x; sraw = fmaf(G2.x, T4.x, sraw); m += T4.x; q = fmaf(T4.x, T4.x, q); \
  T4.y = E4.y * F4.y; sraw = fmaf(G2.y, T4.y, sraw); m += T4.y; q = fmaf(T4.y, T4.y, q); \
  T4.z = E4.z * F4.z; sraw = fmaf(G2.z, T4.z, sraw); m += T4.z; q = fmaf(T4.z, T4.z, q); \
  T4.w = E4.w * F4.w; sraw = fmaf(G2.w, T4.w, sraw); m += T4.w; q = fmaf(T4.w, T4.w, q);

#define AGG_QUAD(A4, T4) \
  A4.x = fmaf(w, T4.x, A4.x); A4.y = fmaf(w, T4.y, A4.y); \
  A4.z = fmaf(w, T4.z, A4.z); A4.w = fmaf(w, T4.w, A4.w);

#define RED_QUAD(A4, MASK) \
  A4.x += __shfl_xor(A4.x, MASK, 64); A4.y += __shfl_xor(A4.y, MASK, 64); \
  A4.z += __shfl_xor(A4.z, MASK, 64); A4.w += __shfl_xor(A4.w, MASK, 64);

// ---- K2: attention + product-LN aggregation, one head per block ----
// 2304 blocks, XCD-PINNED decode: xcd = bid&7 owns 3 (yt,H) combos; X fastest
// within a combo so the combo's 192KB f-set stays hot in that XCD's L2.
// 512 threads = (y:16, ds:2, da:16). LDS: e_sm only (13.5 KB).
__global__ __launch_bounds__(512) void k_attn(
    const float* __restrict__ pF, const float4* __restrict__ murF,
    const float4* __restrict__ murE,
    const float* __restrict__ ln_g, const float* __restrict__ ln_b,
    float* __restrict__ agg) {
  const int bid   = blockIdx.x;
  const int xcd   = bid & 7;
  const int q_    = bid >> 3;            // 0..287
  const int combo = xcd * 3 + q_ / NTOK; // 0..23, pinned per XCD
  const int X     = q_ % NTOK;
  const int y0    = (combo % NYT) * YT;
  const int H     = combo / NYT;

  const int tid = threadIdx.x;
  const int y   = tid >> 5;            // 0..15
  const int ds  = (tid >> 4) & 1;      // d-half
  const int da  = tid & 15;            // a-slice
  const int yy  = y0 + y;
  const int eoff = ds * 16;

  __shared__ float e_sm[NTOK][36];     // 13.5 KB (sole LDS use)

  // stage e-side: e[a] = p(X,a) = pF[a][H][X][.]
  {
    const int g0 = tid;                // 0..511
    const int a = g0 >> 3, qq = g0 & 7;
    *(float4*)&e_sm[a][qq * 4] =
        *(const float4*)&pF[(((size_t)a * HEADS + H) * NTOK + X) * HD + qq * 4];
  }
  if (tid < 256) {
    const int g1 = tid + 512;          // 512..767
    const int a = g1 >> 3, qq = g1 & 7;
    *(float4*)&e_sm[a][qq * 4] =
        *(const float4*)&pF[(((size_t)a * HEADS + H) * NTOK + X) * HD + qq * 4];
  }

  // LN constants: T2=sum g^2, Vb=sum g*b, Wb=sum b^2, Mg2=max g^2
  const float glx = ln_g[tid & 31];
  const float blx = ln_b[tid & 31];
  float T2c = glx * glx, Vbc = glx * blx, Wbc = blx * blx, Mg2 = glx * glx;
  #pragma unroll
  for (int m_ = 1; m_ < 32; m_ <<= 1) {
    T2c += __shfl_xor(T2c, m_, 64);
    Vbc += __shfl_xor(Vbc, m_, 64);
    Wbc += __shfl_xor(Wbc, m_, 64);
    Mg2 = fmaxf(Mg2, __shfl_xor(Mg2, m_, 64));
  }
  // score bound: |sc| <= (64*Mg2 + 2*Wb) / sqrt(32)
  const float SB = (64.f * Mg2 + 2.f * Wbc) * 0.17677669529663687f;

  // g^2 weights for this lane's d-range (reloaded in epilogue, not kept live)
  float4 g2q0, g2q1, g2q2, g2q3;
  {
    const float4 t0 = *(const float4*)&ln_g[eoff];
    const float4 t1 = *(const float4*)&ln_g[eoff + 4];
    const float4 t2 = *(const float4*)&ln_g[eoff + 8];
    const float4 t3 = *(const float4*)&ln_g[eoff + 12];
    g2q0.x = t0.x*t0.x; g2q0.y = t0.y*t0.y; g2q0.z = t0.z*t0.z; g2q0.w = t0.w*t0.w;
    g2q1.x = t1.x*t1.x; g2q1.y = t1.y*t1.y; g2q1.z = t1.z*t1.z; g2q1.w = t1.w*t1.w;
    g2q2.x = t2.x*t2.x; g2q2.y = t2.y*t2.y; g2q2.z = t2.z*t2.z; g2q2.w = t2.w*t2.w;
    g2q3.x = t3.x*t3.x; g2q3.y = t3.y*t3.y; g2q3.z = t3.z*t3.z; g2q3.w = t3.w*t3.w;
  }
  __syncthreads();

  // dense streams: pF[yy][H][a][.], murF[yy][H][a], murE[X][H][a]
  const float* fbase  = pF + (((size_t)yy * HEADS + H) * NTOK) * HD + eoff;
  const float4* mfb   = murF + ((size_t)yy * HEADS + H) * NTOK;
  const float4* meb   = murE + ((size_t)X * HEADS + H) * NTOK;

  float4 acc0 = {0,0,0,0}, acc1 = {0,0,0,0}, acc2 = {0,0,0,0}, acc3 = {0,0,0,0};
  float den = 0.f, cc = 0.f;

  #pragma unroll 2
  for (int ia = 0; ia < 6; ++ia) {
    const int a = ia * 16 + da;
    const float4* fp = (const float4*)(fbase + (size_t)a * HD);
    const float4 f0 = fp[0], f1 = fp[1], f2 = fp[2], f3 = fp[3];
    const float4 mrF = mfb[a];
    const float4 mrE = meb[a];
    const float4 e0 = *(const float4*)&e_sm[a][eoff];
    const float4 e1 = *(const float4*)&e_sm[a][eoff + 4];
    const float4 e2 = *(const float4*)&e_sm[a][eoff + 8];
    const float4 e3 = *(const float4*)&e_sm[a][eoff + 12];

    float sraw = 0.f, m = 0.f, q = 0.f;
    float4 t0, t1, t2, t3;
    PR_QUAD(e0, f0, g2q0, t0);
    PR_QUAD(e1, f1, g2q1, t1);
    PR_QUAD(e2, f2, g2q2, t2);
    PR_QUAD(e3, f3, g2q3, t3);

    // combine d-halves (xor ds bit)
    sraw += __shfl_xor(sraw, 16, 64);
    m    += __shfl_xor(m,    16, 64);
    q    += __shfl_xor(q,    16, 64);

    // LN'd score from raw moments
    const float muE = mrE.x, rE = mrE.y, Sg2E = mrE.z, SgbE = mrE.w;
    const float muF = mrF.x, rF = mrF.y, Sg2F = mrF.z, SgbF = mrF.w;
    const float inner = sraw - muF * Sg2E - muE * Sg2F + muE * muF * T2c;
    const float sfull = rE * rF * inner
                      + rE * (SgbE - muE * Vbc)
                      + rF * (SgbF - muF * Vbc) + Wbc;
    const float sc = sfull * 0.17677669529663687f;   // 1/sqrt(32)

    // product-LN stats
    const float mu = m * (1.f / HD);
    const float var = fmaxf(fmaf(-mu, mu, q * (1.f / HD)), 0.f);
    const float r = rsqrtf(var + 1e-5f);

    const float ex = __expf(sc - SB);   // <= 1 by construction
    const float w = ex * r;
    den += ex;
    cc  = fmaf(w, mu, cc);
    AGG_QUAD(acc0, t0);
    AGG_QUAD(acc1, t1);
    AGG_QUAD(acc2, t2);
    AGG_QUAD(acc3, t3);
  }

  // cross-a reduction over the 16 da lanes
  #pragma unroll
  for (int mask = 1; mask <= 8; mask <<= 1) {
    den += __shfl_xor(den, mask, 64);
    cc  += __shfl_xor(cc,  mask, 64);
    RED_QUAD(acc0, mask);
    RED_QUAD(acc1, mask);
    RED_QUAD(acc2, mask);
    RED_QUAD(acc3, mask);
  }

  if (da == 0) {
    const float4 gq0 = *(const float4*)&ln_g[eoff];
    const float4 gq1 = *(const float4*)&ln_g[eoff + 4];
    const float4 gq2 = *(const float4*)&ln_g[eoff + 8];
    const float4 gq3 = *(const float4*)&ln_g[eoff + 12];
    const float4 bq0 = *(const float4*)&ln_b[eoff];
    const float4 bq1 = *(const float4*)&ln_b[eoff + 4];
    const float4 bq2 = *(const float4*)&ln_b[eoff + 8];
    const float4 bq3 = *(const float4*)&ln_b[eoff + 12];
    const float inv = 1.f / den;
    float4 o0, o1, o2, o3;
    o0.x = fmaf(gq0.x, (acc0.x - cc) * inv, bq0.x);
    o0.y = fmaf(gq0.y, (acc0.y - cc) * inv, bq0.y);
    o0.z = fmaf(gq0.z, (acc0.z - cc) * inv, bq0.z);
    o0.w = fmaf(gq0.w, (acc0.w - cc) * inv, bq0.w);
    o1.x = fmaf(gq1.x, (acc1.x - cc) * inv, bq1.x);
    o1.y = fmaf(gq1.y, (acc1.y - cc) * inv, bq1.y);
    o1.z = fmaf(gq1.z, (acc1.z - cc) * inv, bq1.z);
    o1.w = fmaf(gq1.w, (acc1.w - cc) * inv, bq1.w);
    o2.x = fmaf(gq2.x, (acc2.x - cc) * inv, bq2.x);
    o2.y = fmaf(gq2.y, (acc2.y - cc) * inv, bq2.y);
    o2.z = fmaf(gq2.z, (acc2.z - cc) * inv, bq2.z);
    o2.w = fmaf(gq2.w, (acc2.w - cc) * inv, bq2.w);
    o3.x = fmaf(gq3.x, (acc3.x - cc) * inv, bq3.x);
    o3.y = fmaf(gq3.y, (acc3.y - cc) * inv, bq3.y);
    o3.z = fmaf(gq3.z, (acc3.z - cc) * inv, bq3.z);
    o3.w = fmaf(gq3.w, (acc3.w - cc) * inv, bq3.w);
    float* op = agg + ((size_t)(X * NTOK + yy)) * EMBED + H * HD + eoff;
    *(float4*)&op[0]  = o0;
    *(float4*)&op[4]  = o1;
    *(float4*)&op[8]  = o2;
    *(float4*)&op[12] = o3;
  }
}

// ---- K3: out = LN([x, agg] @ Wf + bf) ----
// 1152 blocks x 256 threads, 8 rows per block
__global__ __launch_bounds__(256) void k_final(
    const float* __restrict__ x, const float* __restrict__ agg,
    const float* __restrict__ Wf, const float* __restrict__ bf,
    const float* __restrict__ g2, const float* __restrict__ b2,
    float* __restrict__ out) {
  const int r0 = blockIdx.x * 8;
  const int tid = threadIdx.x;
  const int e = tid & 127;
  const int rh = tid >> 7;               // rows rh*4 .. rh*4+3
  __shared__ float ct[2 * EMBED][12];    // transposed [x|agg], 12.3 KB
  __shared__ float red_sm[4][4][2];

  #pragma unroll
  for (int i = 0; i < 8; ++i) {
    const int g = tid + i * 256;         // 0..2047
    const int yl = g >> 8, col = g & 255;
    const size_t row = (size_t)(r0 + yl);
    const float v = (col < 128) ? x[row * EMBED + col]
                                : agg[row * EMBED + (col - 128)];
    ct[col][yl] = v;
  }
  __syncthreads();

  const float bias = bf[e];
  float acc4[4] = {bias, bias, bias, bias};
  #pragma unroll 8
  for (int i = 0; i < 2 * EMBED; ++i) {
    const float wv = Wf[(size_t)i * EMBED + e];
    const float4 c0 = *(const float4*)&ct[i][rh * 4];
    acc4[0] = fmaf(wv, c0.x, acc4[0]); acc4[1] = fmaf(wv, c0.y, acc4[1]);
    acc4[2] = fmaf(wv, c0.z, acc4[2]); acc4[3] = fmaf(wv, c0.w, acc4[3]);
  }

  const int wid = tid >> 6;
  #pragma unroll
  for (int k = 0; k < 4; ++k) {
    float s1 = acc4[k], s2 = acc4[k] * acc4[k];
    #pragma unroll
    for (int m_ = 1; m_ < 64; m_ <<= 1) {
      s1 += __shfl_xor(s1, m_, 64);
      s2 += __shfl_xor(s2, m_, 64);
    }
    if ((tid & 63) == 0) { red_sm[wid][k][0] = s1; red_sm[wid][k][1] = s2; }
  }
  __syncthreads();

  const float gg = g2[e], bb = b2[e];
  #pragma unroll
  for (int k = 0; k < 4; ++k) {
    const float S1 = red_sm[wid][k][0] + red_sm[wid ^ 1][k][0];
    const float S2 = red_sm[wid][k][1] + red_sm[wid ^ 1][k][1];
    const float mu = S1 * (1.f / EMBED);
    const float var = fmaxf(S2 * (1.f / EMBED) - mu * mu, 0.f);
    const float rstd = rsqrtf(var + 1e-5f);
    out[(size_t)(r0 + rh * 4 + k) * EMBED + e] = (acc4[k] - mu) * rstd * gg + bb;
  }
}

extern "C" void kernel_launch(void* const* d_in, const int* in_sizes, int n_in,
                              void* d_out, int out_size, void* d_ws, size_t ws_size,
                              hipStream_t stream) {
  const float* x    = (const float*)d_in[0];
  const float* W    = (const float*)d_in[1];
  const float* b    = (const float*)d_in[2];
  const float* ln_g = (const float*)d_in[3];
  const float* ln_b = (const float*)d_in[4];
  const float* Wf   = (const float*)d_in[5];
  const float* bf   = (const float*)d_in[6];
  const float* g2   = (const float*)d_in[7];
  const float* b2   = (const float*)d_in[8];
  float* out = (float*)d_out;

  float*  pF   = (float*)d_ws;                         // NROW*128 floats
  float4* murF = (float4*)(pF + (size_t)NROW * EMBED); // NROW*4 float4
  float4* murE = murF + (size_t)NROW * HEADS;          // NROW*4 float4
  float*  agg  = (float*)(murE + (size_t)NROW * HEADS);

  k_proj<<<NROW / 4, 128, 0, stream>>>(x, W, b, ln_g, ln_b, pF, murF, murE);
  k_attn<<<NTOK * NYT * HEADS, 512, 0, stream>>>(pF, murF, murE, ln_g, ln_b, agg);
  k_final<<<NROW / 8, 256, 0, stream>>>(x, agg, Wf, bf, g2, b2, out);
}